// Round 1
// baseline (363.860 us; speedup 1.0000x reference)
//
#include <hip/hip_runtime.h>
#include <hip/hip_bf16.h>

#define B_   32
#define CIN  96
#define COUT 96
#define NP   3136
#define NE   8
#define HIDD 576

typedef short bf16x8 __attribute__((ext_vector_type(8)));
typedef float f32x4 __attribute__((ext_vector_type(4)));

__device__ __forceinline__ unsigned short f2bf(float f) {
  __hip_bfloat16 h = __float2bfloat16(f);
  unsigned short u; __builtin_memcpy(&u, &h, 2); return u;
}
__device__ __forceinline__ float bf2f(unsigned short u) {
  unsigned int v = ((unsigned int)u) << 16;
  float f; __builtin_memcpy(&f, &v, 4); return f;
}

// ---------------- kernel 1: transpose x -> x_t[b][p][c] bf16, + channel sums --
__global__ __launch_bounds__(256) void k_transpose(const float* __restrict__ x,
                                                   unsigned short* __restrict__ xt,
                                                   float* __restrict__ xmean) {
  __shared__ float tile[CIN][65];
  int bi = blockIdx.x; int b = bi / 49, pt = bi % 49; int p0 = pt * 64;
  int t = threadIdx.x;
  for (int j = t; j < CIN * 64; j += 256) {
    int c = j >> 6, pi = j & 63;
    tile[c][pi] = x[((size_t)(b * CIN + c)) * NP + p0 + pi];
  }
  __syncthreads();
  if (t < CIN) {
    float s = 0.f;
    for (int i = 0; i < 64; ++i) s += tile[t][i];
    atomicAdd(xmean + b * CIN + t, s);
  }
  for (int j = t; j < 64 * CIN; j += 256) {
    int p = j / CIN, c = j % CIN;
    xt[((size_t)(b * NP + p0 + p)) * CIN + c] = f2bf(tile[c][p]);
  }
}

// ---------------- kernel 2: routers r1 (expand) and r_blk (project) ----------
__global__ __launch_bounds__(64) void k_router1(const float* __restrict__ xmean,
    const float* __restrict__ wr1, const float* __restrict__ br1,
    const float* __restrict__ wr3, const float* __restrict__ br3,
    float* __restrict__ r1, float* __restrict__ rblk) {
  int bi = blockIdx.x; int lane = threadIdx.x;
  const float* wr; const float* br; float* dst; int id;
  if (bi < 256) { wr = wr1; br = br1; dst = r1;   id = bi; }
  else          { wr = wr3; br = br3; dst = rblk; id = bi - 256; }
  int b = id >> 3, e = id & 7;
  float s = 0.f;
  for (int c = lane; c < CIN; c += 64)
    s += xmean[b * CIN + c] * (1.0f / NP) * wr[e * CIN + c];
  s += __shfl_xor(s, 1);  s += __shfl_xor(s, 2);  s += __shfl_xor(s, 4);
  s += __shfl_xor(s, 8);  s += __shfl_xor(s, 16); s += __shfl_xor(s, 32);
  if (lane == 0) dst[id] = 1.0f / (1.0f + __expf(-(s + br[e])));
}

// ---------------- kernel 3: BN scale/bias precompute -------------------------
__global__ __launch_bounds__(256) void k_bnprep(
    const float* g1, const float* bt1, const float* m1, const float* v1,
    const float* g2, const float* bt2, const float* m2, const float* v2,
    const float* g3, const float* bt3, const float* m3, const float* v3,
    float* sc1, float* bi1, float* sc2, float* bi2, float* sc3, float* bi3) {
  int i = blockIdx.x * 256 + threadIdx.x;
  if (i < HIDD) {
    float s = g1[i] * rsqrtf(v1[i] + 1e-5f); sc1[i] = s; bi1[i] = bt1[i] - m1[i] * s;
  } else if (i < 2 * HIDD) {
    int c = i - HIDD;
    float s = g2[c] * rsqrtf(v2[c] + 1e-5f); sc2[c] = s; bi2[c] = bt2[c] - m2[c] * s;
  } else if (i < 2 * HIDD + COUT) {
    int c = i - 2 * HIDD;
    float s = g3[c] * rsqrtf(v3[c] + 1e-5f); sc3[c] = s; bi3[c] = bt3[c] - m3[c] * s;
  }
}

// ---------------- kernel 4: mix expert weights -> bf16 -----------------------
__global__ __launch_bounds__(256) void k_mixw(
    const float* __restrict__ w1, const float* __restrict__ r1, unsigned short* __restrict__ w1c,
    const float* __restrict__ w3, const float* __restrict__ rblk, unsigned short* __restrict__ w3c) {
  __shared__ float rsh[256];
  int bi = blockIdx.x; int t = threadIdx.x;
  const float* w; const float* r; unsigned short* dst; int oc0;
  if (bi < 216) { w = w1; r = r1;   dst = w1c; oc0 = bi * 256; }
  else          { w = w3; r = rblk; dst = w3c; oc0 = (bi - 216) * 256; }
  rsh[t] = r[t];
  __syncthreads();
  int oc = oc0 + t;
  float wv[NE];
#pragma unroll
  for (int e = 0; e < NE; ++e) wv[e] = w[(size_t)e * 55296 + oc];
  for (int b = 0; b < B_; ++b) {
    float a = 0.f;
#pragma unroll
    for (int e = 0; e < NE; ++e) a += rsh[b * 8 + e] * wv[e];
    dst[(size_t)b * 55296 + oc] = f2bf(a);
  }
}

// ---------------- kernel 5: expand GEMM (bf16 MFMA) + BN + ReLU6 + ysum ------
// Y[b][o][p] = relu6(bn1( sum_c w1c[b][o][c] * x_t[b][p][c] ))
__global__ __launch_bounds__(256) void k_expand(const unsigned short* __restrict__ xt,
    const unsigned short* __restrict__ w1c, const float* __restrict__ sc1,
    const float* __restrict__ bi1, unsigned short* __restrict__ y,
    float* __restrict__ ysum) {
  __shared__ unsigned short As[64 * 104];
  __shared__ unsigned short Bs[64 * 104];
  int t = threadIdx.x;
  int p0 = blockIdx.x * 64, o0 = blockIdx.y * 64, b = blockIdx.z;
  const unsigned short* ag = w1c + (size_t)b * 55296 + (size_t)o0 * 96;
  const unsigned short* bg = xt + ((size_t)b * NP + p0) * 96;
  for (int j = t; j < 768; j += 256) {
    int r = j / 12, ch = j % 12;
    *(int4*)(As + r * 104 + ch * 8) = *(const int4*)(ag + r * 96 + ch * 8);
    *(int4*)(Bs + r * 104 + ch * 8) = *(const int4*)(bg + r * 96 + ch * 8);
  }
  __syncthreads();
  int lane = t & 63, wv = t >> 6;
  int m = lane & 15, q = lane >> 4;
  f32x4 acc[4];
#pragma unroll
  for (int nt = 0; nt < 4; ++nt) acc[nt] = 0.f;
#pragma unroll
  for (int kk = 0; kk < 3; ++kk) {
    bf16x8 af = *(const bf16x8*)(As + (wv * 16 + m) * 104 + kk * 32 + q * 8);
#pragma unroll
    for (int nt = 0; nt < 4; ++nt) {
      bf16x8 bfb = *(const bf16x8*)(Bs + (nt * 16 + m) * 104 + kk * 32 + q * 8);
      acc[nt] = __builtin_amdgcn_mfma_f32_16x16x32_bf16(af, bfb, acc[nt], 0, 0, 0);
    }
  }
#pragma unroll
  for (int i = 0; i < 4; ++i) {
    int ol = wv * 16 + q * 4 + i; int o = o0 + ol;
    float sc = sc1[o], bb = bi1[o];
    float rs = 0.f;
    size_t base = ((size_t)(b * HIDD + o)) * NP + p0;
#pragma unroll
    for (int nt = 0; nt < 4; ++nt) {
      float v = acc[nt][i] * sc + bb;
      v = fminf(fmaxf(v, 0.f), 6.f);
      y[base + nt * 16 + m] = f2bf(v);
      rs += v;
    }
    rs += __shfl_xor(rs, 1); rs += __shfl_xor(rs, 2);
    rs += __shfl_xor(rs, 4); rs += __shfl_xor(rs, 8);
    if (m == 0) atomicAdd(ysum + b * HIDD + o, rs);
  }
}

// ---------------- kernel 6: router r2 (depthwise) ----------------------------
__global__ __launch_bounds__(64) void k_router2(const float* __restrict__ ysum,
    const float* __restrict__ wr2, const float* __restrict__ br2, float* __restrict__ r2) {
  int id = blockIdx.x; int lane = threadIdx.x;
  int b = id >> 3, e = id & 7;
  float s = 0.f;
  for (int h = lane; h < HIDD; h += 64)
    s += ysum[b * HIDD + h] * (1.0f / NP) * wr2[e * HIDD + h];
  s += __shfl_xor(s, 1);  s += __shfl_xor(s, 2);  s += __shfl_xor(s, 4);
  s += __shfl_xor(s, 8);  s += __shfl_xor(s, 16); s += __shfl_xor(s, 32);
  if (lane == 0) r2[id] = 1.0f / (1.0f + __expf(-(s + br2[e])));
}

// ---------------- kernel 7: depthwise 3x3 (in-place on y) + BN + ReLU6 -------
__global__ __launch_bounds__(256) void k_dwise(unsigned short* __restrict__ y,
    const float* __restrict__ r2, const float* __restrict__ w2,
    const float* __restrict__ sc2, const float* __restrict__ bi2) {
  __shared__ float pl[NP];
  __shared__ float kwl[9];
  __shared__ float scb[2];
  int bc = blockIdx.x; int b = bc / HIDD, c = bc % HIDD;
  int t = threadIdx.x;
  unsigned short* yp = y + (size_t)bc * NP;
  for (int i = t; i < NP; i += 256) pl[i] = bf2f(yp[i]);
  if (t < 9) {
    float s = 0.f;
#pragma unroll
    for (int e = 0; e < 8; ++e) s += r2[b * 8 + e] * w2[((size_t)e * HIDD + c) * 9 + t];
    kwl[t] = s;
  }
  if (t == 9)  scb[0] = sc2[c];
  if (t == 10) scb[1] = bi2[c];
  __syncthreads();
  float k0 = kwl[0], k1 = kwl[1], k2 = kwl[2], k3 = kwl[3], k4 = kwl[4],
        k5 = kwl[5], k6 = kwl[6], k7 = kwl[7], k8 = kwl[8];
  float ss = scb[0], bb = scb[1];
  for (int i = t; i < NP; i += 256) {
    int h = i / 56, w = i - h * 56;
    float a = 0.f;
    if (h > 0) {
      int j = i - 56;
      if (w > 0)  a += pl[j - 1] * k0;
      a += pl[j] * k1;
      if (w < 55) a += pl[j + 1] * k2;
    }
    {
      if (w > 0)  a += pl[i - 1] * k3;
      a += pl[i] * k4;
      if (w < 55) a += pl[i + 1] * k5;
    }
    if (h < 55) {
      int j = i + 56;
      if (w > 0)  a += pl[j - 1] * k6;
      a += pl[j] * k7;
      if (w < 55) a += pl[j + 1] * k8;
    }
    float v = fminf(fmaxf(a * ss + bb, 0.f), 6.f);
    yp[i] = f2bf(v);
  }
}

// ---------------- kernel 8: project GEMM + BN + residual ---------------------
// out[b][o][p] = bn3( sum_h w3c[b][o][h] * z[b][h][p] ) + x[b][o][p]
__global__ __launch_bounds__(384) void k_project(const unsigned short* __restrict__ z,
    const unsigned short* __restrict__ w3c, const float* __restrict__ sc3,
    const float* __restrict__ bi3, const float* __restrict__ x, float* __restrict__ out) {
  __shared__ unsigned short As[96 * 72];
  __shared__ unsigned short Bs[64 * 72];
  int t = threadIdx.x;
  int p0 = blockIdx.x * 64, b = blockIdx.z;
  const unsigned short* ag = w3c + (size_t)b * 55296;
  const unsigned short* zb = z + (size_t)b * HIDD * NP;
  int lane = t & 63, wv = t >> 6;
  int m = lane & 15, q = lane >> 4;
  f32x4 acc[4];
#pragma unroll
  for (int nt = 0; nt < 4; ++nt) acc[nt] = 0.f;
  for (int c0 = 0; c0 < HIDD; c0 += 64) {
    __syncthreads();
    for (int j = t; j < 768; j += 384) {
      int r = j >> 3, ch = j & 7;
      *(int4*)(As + r * 72 + ch * 8) = *(const int4*)(ag + (size_t)r * 576 + c0 + ch * 8);
    }
    for (int j = t; j < 512; j += 384) {
      int c = j >> 3, pg = j & 7;
      const unsigned short* src = zb + (size_t)(c0 + c) * NP + p0 + pg * 8;
      int4 vv = *(const int4*)src;
      unsigned short el[8]; __builtin_memcpy(el, &vv, 16);
#pragma unroll
      for (int ii = 0; ii < 8; ++ii) Bs[(pg * 8 + ii) * 72 + c] = el[ii];
    }
    __syncthreads();
#pragma unroll
    for (int kk = 0; kk < 2; ++kk) {
      bf16x8 af = *(const bf16x8*)(As + (wv * 16 + m) * 72 + kk * 32 + q * 8);
#pragma unroll
      for (int nt = 0; nt < 4; ++nt) {
        bf16x8 bfb = *(const bf16x8*)(Bs + (nt * 16 + m) * 72 + kk * 32 + q * 8);
        acc[nt] = __builtin_amdgcn_mfma_f32_16x16x32_bf16(af, bfb, acc[nt], 0, 0, 0);
      }
    }
  }
#pragma unroll
  for (int i = 0; i < 4; ++i) {
    int o = wv * 16 + q * 4 + i;
    float sc = sc3[o], bb = bi3[o];
    size_t base = ((size_t)(b * COUT + o)) * NP + p0;
#pragma unroll
    for (int nt = 0; nt < 4; ++nt) {
      float v = acc[nt][i] * sc + bb + x[base + nt * 16 + m];
      out[base + nt * 16 + m] = v;
    }
  }
}

// ---------------- workspace layout (bytes) -----------------------------------
#define OFF_XT    ((size_t)0)           // 19267584
#define OFF_Y     ((size_t)19267584)    // 115605504
#define OFF_W1C   ((size_t)134873088)   // 3538944
#define OFF_W3C   ((size_t)138412032)   // 3538944
#define OFF_XMEAN ((size_t)141950976)   // 12288   (zeroed)
#define OFF_YSUM  ((size_t)141963264)   // 73728   (zeroed)
#define OFF_R1    ((size_t)142036992)   // 1024
#define OFF_RBLK  ((size_t)142038016)   // 1024
#define OFF_R2    ((size_t)142039040)   // 1024
#define OFF_SC1   ((size_t)142040064)   // 2304
#define OFF_BI1   ((size_t)142042368)   // 2304
#define OFF_SC2   ((size_t)142044672)   // 2304
#define OFF_BI2   ((size_t)142046976)   // 2304
#define OFF_SC3   ((size_t)142049280)   // 384
#define OFF_BI3   ((size_t)142049664)   // 384

extern "C" void kernel_launch(void* const* d_in, const int* in_sizes, int n_in,
                              void* d_out, int out_size, void* d_ws, size_t ws_size,
                              hipStream_t stream) {
  const float* x   = (const float*)d_in[0];
  const float* wr1 = (const float*)d_in[1];
  const float* br1 = (const float*)d_in[2];
  const float* w1  = (const float*)d_in[3];
  const float* g1  = (const float*)d_in[4];
  const float* bt1 = (const float*)d_in[5];
  const float* m1  = (const float*)d_in[6];
  const float* v1  = (const float*)d_in[7];
  const float* wr2 = (const float*)d_in[8];
  const float* br2 = (const float*)d_in[9];
  const float* w2  = (const float*)d_in[10];
  const float* g2  = (const float*)d_in[11];
  const float* bt2 = (const float*)d_in[12];
  const float* m2  = (const float*)d_in[13];
  const float* v2  = (const float*)d_in[14];
  const float* w3  = (const float*)d_in[15];
  const float* g3  = (const float*)d_in[16];
  const float* bt3 = (const float*)d_in[17];
  const float* m3  = (const float*)d_in[18];
  const float* v3  = (const float*)d_in[19];
  const float* wr3 = (const float*)d_in[20];
  const float* br3 = (const float*)d_in[21];
  float* out = (float*)d_out;
  char* ws = (char*)d_ws;

  unsigned short* xt   = (unsigned short*)(ws + OFF_XT);
  unsigned short* y    = (unsigned short*)(ws + OFF_Y);
  unsigned short* w1c  = (unsigned short*)(ws + OFF_W1C);
  unsigned short* w3c  = (unsigned short*)(ws + OFF_W3C);
  float* xmean = (float*)(ws + OFF_XMEAN);
  float* ysum  = (float*)(ws + OFF_YSUM);
  float* r1    = (float*)(ws + OFF_R1);
  float* rblk  = (float*)(ws + OFF_RBLK);
  float* r2    = (float*)(ws + OFF_R2);
  float* sc1   = (float*)(ws + OFF_SC1);
  float* bi1   = (float*)(ws + OFF_BI1);
  float* sc2   = (float*)(ws + OFF_SC2);
  float* bi2   = (float*)(ws + OFF_BI2);
  float* sc3   = (float*)(ws + OFF_SC3);
  float* bi3   = (float*)(ws + OFF_BI3);

  // zero the atomic-accumulation buffers (xmean + ysum are contiguous)
  hipMemsetAsync(ws + OFF_XMEAN, 0, 12288 + 73728, stream);

  k_transpose<<<32 * 49, 256, 0, stream>>>(x, xt, xmean);
  k_router1<<<512, 64, 0, stream>>>(xmean, wr1, br1, wr3, br3, r1, rblk);
  k_bnprep<<<5, 256, 0, stream>>>(g1, bt1, m1, v1, g2, bt2, m2, v2, g3, bt3, m3, v3,
                                  sc1, bi1, sc2, bi2, sc3, bi3);
  k_mixw<<<432, 256, 0, stream>>>(w1, r1, w1c, w3, rblk, w3c);
  k_expand<<<dim3(49, 9, 32), 256, 0, stream>>>(xt, w1c, sc1, bi1, y, ysum);
  k_router2<<<256, 64, 0, stream>>>(ysum, wr2, br2, r2);
  k_dwise<<<B_ * HIDD, 256, 0, stream>>>(y, r2, w2, sc2, bi2);
  k_project<<<dim3(49, 1, 32), 384, 0, stream>>>(y, w3c, sc3, bi3, x, out);
}

// Round 2
// 362.008 us; speedup vs baseline: 1.0051x; 1.0051x over previous
//
#include <hip/hip_runtime.h>
#include <hip/hip_bf16.h>

#define B_   32
#define CIN  96
#define COUT 96
#define NP   3136
#define NE   8
#define HIDD 576

typedef short bf16x8 __attribute__((ext_vector_type(8)));
typedef float f32x4 __attribute__((ext_vector_type(4)));

__device__ __forceinline__ unsigned short f2bf(float f) {
  __hip_bfloat16 h = __float2bfloat16(f);
  unsigned short u; __builtin_memcpy(&u, &h, 2); return u;
}
__device__ __forceinline__ float bf2f(unsigned short u) {
  unsigned int v = ((unsigned int)u) << 16;
  float f; __builtin_memcpy(&f, &v, 4); return f;
}

// ---------------- kernel 1: transpose x -> x_t[b][p][c] bf16, + channel sums --
__global__ __launch_bounds__(256) void k_transpose(const float* __restrict__ x,
                                                   unsigned short* __restrict__ xt,
                                                   float* __restrict__ xmean) {
  __shared__ float tile[CIN][65];
  int bi = blockIdx.x; int b = bi / 49, pt = bi % 49; int p0 = pt * 64;
  int t = threadIdx.x;
  for (int j = t; j < CIN * 64; j += 256) {
    int c = j >> 6, pi = j & 63;
    tile[c][pi] = x[((size_t)(b * CIN + c)) * NP + p0 + pi];
  }
  __syncthreads();
  if (t < CIN) {
    float s = 0.f;
    for (int i = 0; i < 64; ++i) s += tile[t][i];
    atomicAdd(xmean + b * CIN + t, s);
  }
  for (int j = t; j < 64 * CIN; j += 256) {
    int p = j / CIN, c = j % CIN;
    xt[((size_t)(b * NP + p0 + p)) * CIN + c] = f2bf(tile[c][p]);
  }
}

// ---------------- kernel 2: routers r1 (expand) and r_blk (project) ----------
__global__ __launch_bounds__(64) void k_router1(const float* __restrict__ xmean,
    const float* __restrict__ wr1, const float* __restrict__ br1,
    const float* __restrict__ wr3, const float* __restrict__ br3,
    float* __restrict__ r1, float* __restrict__ rblk) {
  int bi = blockIdx.x; int lane = threadIdx.x;
  const float* wr; const float* br; float* dst; int id;
  if (bi < 256) { wr = wr1; br = br1; dst = r1;   id = bi; }
  else          { wr = wr3; br = br3; dst = rblk; id = bi - 256; }
  int b = id >> 3, e = id & 7;
  float s = 0.f;
  for (int c = lane; c < CIN; c += 64)
    s += xmean[b * CIN + c] * (1.0f / NP) * wr[e * CIN + c];
  s += __shfl_xor(s, 1);  s += __shfl_xor(s, 2);  s += __shfl_xor(s, 4);
  s += __shfl_xor(s, 8);  s += __shfl_xor(s, 16); s += __shfl_xor(s, 32);
  if (lane == 0) dst[id] = 1.0f / (1.0f + __expf(-(s + br[e])));
}

// ---------------- kernel 3: BN scale/bias precompute -------------------------
__global__ __launch_bounds__(256) void k_bnprep(
    const float* g1, const float* bt1, const float* m1, const float* v1,
    const float* g2, const float* bt2, const float* m2, const float* v2,
    const float* g3, const float* bt3, const float* m3, const float* v3,
    float* sc1, float* bi1, float* sc2, float* bi2, float* sc3, float* bi3) {
  int i = blockIdx.x * 256 + threadIdx.x;
  if (i < HIDD) {
    float s = g1[i] * rsqrtf(v1[i] + 1e-5f); sc1[i] = s; bi1[i] = bt1[i] - m1[i] * s;
  } else if (i < 2 * HIDD) {
    int c = i - HIDD;
    float s = g2[c] * rsqrtf(v2[c] + 1e-5f); sc2[c] = s; bi2[c] = bt2[c] - m2[c] * s;
  } else if (i < 2 * HIDD + COUT) {
    int c = i - 2 * HIDD;
    float s = g3[c] * rsqrtf(v3[c] + 1e-5f); sc3[c] = s; bi3[c] = bt3[c] - m3[c] * s;
  }
}

// ---------------- kernel 4: mix expert weights -> bf16 -----------------------
__global__ __launch_bounds__(256) void k_mixw(
    const float* __restrict__ w1, const float* __restrict__ r1, unsigned short* __restrict__ w1c,
    const float* __restrict__ w3, const float* __restrict__ rblk, unsigned short* __restrict__ w3c) {
  __shared__ float rsh[256];
  int bi = blockIdx.x; int t = threadIdx.x;
  const float* w; const float* r; unsigned short* dst; int oc0;
  if (bi < 216) { w = w1; r = r1;   dst = w1c; oc0 = bi * 256; }
  else          { w = w3; r = rblk; dst = w3c; oc0 = (bi - 216) * 256; }
  rsh[t] = r[t];
  __syncthreads();
  int oc = oc0 + t;
  float wv[NE];
#pragma unroll
  for (int e = 0; e < NE; ++e) wv[e] = w[(size_t)e * 55296 + oc];
  for (int b = 0; b < B_; ++b) {
    float a = 0.f;
#pragma unroll
    for (int e = 0; e < NE; ++e) a += rsh[b * 8 + e] * wv[e];
    dst[(size_t)b * 55296 + oc] = f2bf(a);
  }
}

// ---------------- kernel 5: expand GEMM (bf16 MFMA) + BN + ReLU6 + ysum ------
// Y[b][o][p] = relu6(bn1( sum_c w1c[b][o][c] * x_t[b][p][c] ))
__global__ __launch_bounds__(256) void k_expand(const unsigned short* __restrict__ xt,
    const unsigned short* __restrict__ w1c, const float* __restrict__ sc1,
    const float* __restrict__ bi1, unsigned short* __restrict__ y,
    float* __restrict__ ysum) {
  __shared__ unsigned short As[64 * 104];
  __shared__ unsigned short Bs[64 * 104];
  int t = threadIdx.x;
  int p0 = blockIdx.x * 64, o0 = blockIdx.y * 64, b = blockIdx.z;
  const unsigned short* ag = w1c + (size_t)b * 55296 + (size_t)o0 * 96;
  const unsigned short* bg = xt + ((size_t)b * NP + p0) * 96;
  for (int j = t; j < 768; j += 256) {
    int r = j / 12, ch = j % 12;
    *(int4*)(As + r * 104 + ch * 8) = *(const int4*)(ag + r * 96 + ch * 8);
    *(int4*)(Bs + r * 104 + ch * 8) = *(const int4*)(bg + r * 96 + ch * 8);
  }
  __syncthreads();
  int lane = t & 63, wv = t >> 6;
  int m = lane & 15, q = lane >> 4;
  f32x4 acc[4];
#pragma unroll
  for (int nt = 0; nt < 4; ++nt) acc[nt] = 0.f;
#pragma unroll
  for (int kk = 0; kk < 3; ++kk) {
    bf16x8 af = *(const bf16x8*)(As + (wv * 16 + m) * 104 + kk * 32 + q * 8);
#pragma unroll
    for (int nt = 0; nt < 4; ++nt) {
      bf16x8 bfb = *(const bf16x8*)(Bs + (nt * 16 + m) * 104 + kk * 32 + q * 8);
      acc[nt] = __builtin_amdgcn_mfma_f32_16x16x32_bf16(af, bfb, acc[nt], 0, 0, 0);
    }
  }
#pragma unroll
  for (int i = 0; i < 4; ++i) {
    int ol = wv * 16 + q * 4 + i; int o = o0 + ol;
    float sc = sc1[o], bb = bi1[o];
    float rs = 0.f;
    size_t base = ((size_t)(b * HIDD + o)) * NP + p0;
#pragma unroll
    for (int nt = 0; nt < 4; ++nt) {
      float v = acc[nt][i] * sc + bb;
      v = fminf(fmaxf(v, 0.f), 6.f);
      y[base + nt * 16 + m] = f2bf(v);
      rs += v;
    }
    rs += __shfl_xor(rs, 1); rs += __shfl_xor(rs, 2);
    rs += __shfl_xor(rs, 4); rs += __shfl_xor(rs, 8);
    if (m == 0) atomicAdd(ysum + b * HIDD + o, rs);
  }
}

// ---------------- kernel 6: router r2 (depthwise) ----------------------------
__global__ __launch_bounds__(64) void k_router2(const float* __restrict__ ysum,
    const float* __restrict__ wr2, const float* __restrict__ br2, float* __restrict__ r2) {
  int id = blockIdx.x; int lane = threadIdx.x;
  int b = id >> 3, e = id & 7;
  float s = 0.f;
  for (int h = lane; h < HIDD; h += 64)
    s += ysum[b * HIDD + h] * (1.0f / NP) * wr2[e * HIDD + h];
  s += __shfl_xor(s, 1);  s += __shfl_xor(s, 2);  s += __shfl_xor(s, 4);
  s += __shfl_xor(s, 8);  s += __shfl_xor(s, 16); s += __shfl_xor(s, 32);
  if (lane == 0) r2[id] = 1.0f / (1.0f + __expf(-(s + br2[e])));
}

// ---------------- kernel 6b: premix depthwise taps (fold BN scale in) --------
// kwbuf[plane][12] = {k0*sc .. k8*sc, bias, 0, 0}
__global__ __launch_bounds__(256) void k_kwmix(const float* __restrict__ r2,
    const float* __restrict__ w2, const float* __restrict__ sc2,
    const float* __restrict__ bi2, float* __restrict__ kwbuf) {
  int i = blockIdx.x * 256 + threadIdx.x;
  if (i >= B_ * HIDD) return;
  int b = i / HIDD, c = i - b * HIDD;
  float rr[NE];
#pragma unroll
  for (int e = 0; e < NE; ++e) rr[e] = r2[b * 8 + e];
  float sc = sc2[c];
  float out[12];
#pragma unroll
  for (int k = 0; k < 9; ++k) {
    float s = 0.f;
#pragma unroll
    for (int e = 0; e < NE; ++e) s += rr[e] * w2[((size_t)e * HIDD + c) * 9 + k];
    out[k] = s * sc;
  }
  out[9] = bi2[c]; out[10] = 0.f; out[11] = 0.f;
#pragma unroll
  for (int k = 0; k < 12; ++k) kwbuf[(size_t)i * 12 + k] = out[k];
}

// ---------------- kernel 7: depthwise 3x3, register-based, in-place ----------
// One block owns one (b,c) plane. Thread = one 8-wide octet of one row.
// All loads -> regs, __syncthreads (vmcnt drain), then stores. No LDS stencil.
__device__ __forceinline__ void load_row10(const unsigned short* __restrict__ row,
                                           int w0, float* o) {
  int4 v = *(const int4*)(row + w0);
  unsigned short e[8]; __builtin_memcpy(e, &v, 16);
  o[0] = (w0 > 0) ? bf2f(row[w0 - 1]) : 0.f;
#pragma unroll
  for (int i = 0; i < 8; ++i) o[1 + i] = bf2f(e[i]);
  o[9] = (w0 < 48) ? bf2f(row[w0 + 8]) : 0.f;
}

__global__ __launch_bounds__(448) void k_dwise2(unsigned short* __restrict__ y,
                                                const float* __restrict__ kwbuf) {
  int plane = blockIdx.x;            // b*HIDD + c
  int t = threadIdx.x;               // 0..447; 392 active (56 rows x 7 octets)
  unsigned short* yp = y + (size_t)plane * NP;
  const float* kw = kwbuf + (size_t)plane * 12;
  float4 ka = *(const float4*)kw;        // k0 k1 k2 k3 (BN scale folded in)
  float4 kb = *(const float4*)(kw + 4);  // k4 k5 k6 k7
  float4 kc = *(const float4*)(kw + 8);  // k8 bias - -
  bool act = t < 392;
  int h = 0, w0 = 0;
  float rm[10], r0[10], rp[10];
#pragma unroll
  for (int i = 0; i < 10; ++i) { rm[i] = 0.f; r0[i] = 0.f; rp[i] = 0.f; }
  if (act) {
    h = t / 7; w0 = (t - h * 7) * 8;
    load_row10(yp + h * 56, w0, r0);
    if (h > 0)  load_row10(yp + (h - 1) * 56, w0, rm);
    if (h < 55) load_row10(yp + (h + 1) * 56, w0, rp);
  }
  __syncthreads();   // all reads of this plane complete before any in-place store
  if (act) {
    unsigned short pk[8];
#pragma unroll
    for (int i = 0; i < 8; ++i) {
      float o = rm[i] * ka.x + rm[i + 1] * ka.y + rm[i + 2] * ka.z
              + r0[i] * ka.w + r0[i + 1] * kb.x + r0[i + 2] * kb.y
              + rp[i] * kb.z + rp[i + 1] * kb.w + rp[i + 2] * kc.x + kc.y;
      o = fminf(fmaxf(o, 0.f), 6.f);
      pk[i] = f2bf(o);
    }
    int4 vv; __builtin_memcpy(&vv, pk, 16);
    *(int4*)(yp + h * 56 + w0) = vv;
  }
}

// ---------------- kernel 8: project GEMM + BN + residual ---------------------
// out[b][o][p] = bn3( sum_h w3c[b][o][h] * z[b][h][p] ) + x[b][o][p]
__global__ __launch_bounds__(384) void k_project(const unsigned short* __restrict__ z,
    const unsigned short* __restrict__ w3c, const float* __restrict__ sc3,
    const float* __restrict__ bi3, const float* __restrict__ x, float* __restrict__ out) {
  __shared__ unsigned short As[96 * 72];
  __shared__ unsigned short Bs[64 * 72];
  int t = threadIdx.x;
  int p0 = blockIdx.x * 64, b = blockIdx.z;
  const unsigned short* ag = w3c + (size_t)b * 55296;
  const unsigned short* zb = z + (size_t)b * HIDD * NP;
  int lane = t & 63, wv = t >> 6;
  int m = lane & 15, q = lane >> 4;
  f32x4 acc[4];
#pragma unroll
  for (int nt = 0; nt < 4; ++nt) acc[nt] = 0.f;
  for (int c0 = 0; c0 < HIDD; c0 += 64) {
    __syncthreads();
    for (int j = t; j < 768; j += 384) {
      int r = j >> 3, ch = j & 7;
      *(int4*)(As + r * 72 + ch * 8) = *(const int4*)(ag + (size_t)r * 576 + c0 + ch * 8);
    }
    for (int j = t; j < 512; j += 384) {
      int c = j >> 3, pg = j & 7;
      const unsigned short* src = zb + (size_t)(c0 + c) * NP + p0 + pg * 8;
      int4 vv = *(const int4*)src;
      unsigned short el[8]; __builtin_memcpy(el, &vv, 16);
#pragma unroll
      for (int ii = 0; ii < 8; ++ii) Bs[(pg * 8 + ii) * 72 + c] = el[ii];
    }
    __syncthreads();
#pragma unroll
    for (int kk = 0; kk < 2; ++kk) {
      bf16x8 af = *(const bf16x8*)(As + (wv * 16 + m) * 72 + kk * 32 + q * 8);
#pragma unroll
      for (int nt = 0; nt < 4; ++nt) {
        bf16x8 bfb = *(const bf16x8*)(Bs + (nt * 16 + m) * 72 + kk * 32 + q * 8);
        acc[nt] = __builtin_amdgcn_mfma_f32_16x16x32_bf16(af, bfb, acc[nt], 0, 0, 0);
      }
    }
  }
#pragma unroll
  for (int i = 0; i < 4; ++i) {
    int o = wv * 16 + q * 4 + i;
    float sc = sc3[o], bb = bi3[o];
    size_t base = ((size_t)(b * COUT + o)) * NP + p0;
#pragma unroll
    for (int nt = 0; nt < 4; ++nt) {
      float v = acc[nt][i] * sc + bb + x[base + nt * 16 + m];
      out[base + nt * 16 + m] = v;
    }
  }
}

// ---------------- workspace layout (bytes) -----------------------------------
#define OFF_XT    ((size_t)0)           // 19267584 (dead after expand; kwbuf aliases)
#define OFF_Y     ((size_t)19267584)    // 115605504
#define OFF_W1C   ((size_t)134873088)   // 3538944
#define OFF_W3C   ((size_t)138412032)   // 3538944
#define OFF_XMEAN ((size_t)141950976)   // 12288   (zeroed)
#define OFF_YSUM  ((size_t)141963264)   // 73728   (zeroed)
#define OFF_R1    ((size_t)142036992)   // 1024
#define OFF_RBLK  ((size_t)142038016)   // 1024
#define OFF_R2    ((size_t)142039040)   // 1024
#define OFF_SC1   ((size_t)142040064)   // 2304
#define OFF_BI1   ((size_t)142042368)   // 2304
#define OFF_SC2   ((size_t)142044672)   // 2304
#define OFF_BI2   ((size_t)142046976)   // 2304
#define OFF_SC3   ((size_t)142049280)   // 384
#define OFF_BI3   ((size_t)142049664)   // 384
#define OFF_KW    OFF_XT                // 884736 (aliases xt after expand)

extern "C" void kernel_launch(void* const* d_in, const int* in_sizes, int n_in,
                              void* d_out, int out_size, void* d_ws, size_t ws_size,
                              hipStream_t stream) {
  const float* x   = (const float*)d_in[0];
  const float* wr1 = (const float*)d_in[1];
  const float* br1 = (const float*)d_in[2];
  const float* w1  = (const float*)d_in[3];
  const float* g1  = (const float*)d_in[4];
  const float* bt1 = (const float*)d_in[5];
  const float* m1  = (const float*)d_in[6];
  const float* v1  = (const float*)d_in[7];
  const float* wr2 = (const float*)d_in[8];
  const float* br2 = (const float*)d_in[9];
  const float* w2  = (const float*)d_in[10];
  const float* g2  = (const float*)d_in[11];
  const float* bt2 = (const float*)d_in[12];
  const float* m2  = (const float*)d_in[13];
  const float* v2  = (const float*)d_in[14];
  const float* w3  = (const float*)d_in[15];
  const float* g3  = (const float*)d_in[16];
  const float* bt3 = (const float*)d_in[17];
  const float* m3  = (const float*)d_in[18];
  const float* v3  = (const float*)d_in[19];
  const float* wr3 = (const float*)d_in[20];
  const float* br3 = (const float*)d_in[21];
  float* out = (float*)d_out;
  char* ws = (char*)d_ws;

  unsigned short* xt   = (unsigned short*)(ws + OFF_XT);
  unsigned short* y    = (unsigned short*)(ws + OFF_Y);
  unsigned short* w1c  = (unsigned short*)(ws + OFF_W1C);
  unsigned short* w3c  = (unsigned short*)(ws + OFF_W3C);
  float* xmean = (float*)(ws + OFF_XMEAN);
  float* ysum  = (float*)(ws + OFF_YSUM);
  float* r1    = (float*)(ws + OFF_R1);
  float* rblk  = (float*)(ws + OFF_RBLK);
  float* r2    = (float*)(ws + OFF_R2);
  float* sc1   = (float*)(ws + OFF_SC1);
  float* bi1   = (float*)(ws + OFF_BI1);
  float* sc2   = (float*)(ws + OFF_SC2);
  float* bi2   = (float*)(ws + OFF_BI2);
  float* sc3   = (float*)(ws + OFF_SC3);
  float* bi3   = (float*)(ws + OFF_BI3);
  float* kwbuf = (float*)(ws + OFF_KW);

  // zero the atomic-accumulation buffers (xmean + ysum are contiguous)
  hipMemsetAsync(ws + OFF_XMEAN, 0, 12288 + 73728, stream);

  k_transpose<<<32 * 49, 256, 0, stream>>>(x, xt, xmean);
  k_router1<<<512, 64, 0, stream>>>(xmean, wr1, br1, wr3, br3, r1, rblk);
  k_bnprep<<<5, 256, 0, stream>>>(g1, bt1, m1, v1, g2, bt2, m2, v2, g3, bt3, m3, v3,
                                  sc1, bi1, sc2, bi2, sc3, bi3);
  k_mixw<<<432, 256, 0, stream>>>(w1, r1, w1c, w3, rblk, w3c);
  k_expand<<<dim3(49, 9, 32), 256, 0, stream>>>(xt, w1c, sc1, bi1, y, ysum);
  k_router2<<<256, 64, 0, stream>>>(ysum, wr2, br2, r2);
  k_kwmix<<<72, 256, 0, stream>>>(r2, w2, sc2, bi2, kwbuf);
  k_dwise2<<<B_ * HIDD, 448, 0, stream>>>(y, kwbuf);
  k_project<<<dim3(49, 1, 32), 384, 0, stream>>>(y, w3c, sc3, bi3, x, out);
}